// Round 7
// baseline (36.577 us; speedup 1.0000x reference)
//
#include <hip/hip_runtime.h>
#include <hip/hip_bf16.h>
#include <cstdint>

#define K_DIM 1024
#define N_DIM 128
#define BM 64
#define BK 32
#define NT (K_DIM / BK)   // 32 K-tiles

typedef __attribute__((ext_vector_type(8))) short bf16x8;
typedef __attribute__((ext_vector_type(4))) float f32x4;
typedef unsigned short u16;
typedef unsigned int u32;

__device__ __forceinline__ float pwbq(float w) {
  w = fminf(fmaxf(w, -1.0f), 1.0f);
  return rintf(w * 127.0f) * (1.0f / 127.0f);
}

// float -> bf16 round-to-nearest-even (finite inputs only)
__device__ __forceinline__ u16 f2bf(float f) {
  union { float f; u32 u; } v; v.f = f;
  u32 r = v.u + 0x7FFFu + ((v.u >> 16) & 1u);
  return (u16)(r >> 16);
}

// Wimg[t][col][j] : [32][128][32] bf16 = quantize(W[(t*32+j)*128 + col]).
// Layout + read math verified end-to-end by round 4 (passed, absmax 0.03).
__global__ __launch_bounds__(256) void quantW_kernel(const float* __restrict__ W,
                                                     u16* __restrict__ Wimg) {
  int H = blockIdx.x * 256 + threadIdx.x;   // 0 .. 131071
  int t = H >> 12;
  int col = (H >> 5) & 127;
  int j = H & 31;
  Wimg[H] = f2bf(pwbq(W[(t * 32 + j) * N_DIM + col]));
}

// Correctness-insurance fallback (only if d_ws is unusably small).
__global__ __launch_bounds__(256) void naive_kernel(const float* __restrict__ x,
                                                    const float* __restrict__ W,
                                                    const float* __restrict__ b,
                                                    float* __restrict__ out, int total) {
  int idx = blockIdx.x * 256 + threadIdx.x;
  if (idx >= total) return;
  int m = idx >> 7, n = idx & 127;
  float acc = pwbq(b[n]);
  for (int k = 0; k < K_DIM; ++k)
    acc = fmaf(x[(size_t)m * K_DIM + k], pwbq(W[k * N_DIM + n]), acc);
  out[idx] = acc;
}

// out[M][128] = x[M][1024] @ Wq + bq
// 256 thr / 4 waves; wave tile 32 rows x 64 cols (8 MFMA/iter). BM=64, grid 512.
// A: reg-staged (global->reg->cvt bf16->ds_write). B: global_load_lds from Wimg.
// Ring-3 LDS. Per iter: vmcnt(2) -> WRITEA(t+1) -> lgkmcnt(0) -> sched_barrier
// -> s_barrier -> issue stage(t+2) -> compute(t).
// Race-safety: stage(t+2) writes buf (t+2)%3 == (t-1)%3 AFTER barrier(t), i.e.
// after all waves finished compute(t-1). WRITEA(t+1) targets (t+1)%3, disjoint
// from (t-1)%3 and t%3. All LDS access patterns are bank-uniform (8/bank).
__global__ __launch_bounds__(256, 2) void pwb_gemm(
    const float* __restrict__ x,
    const u16* __restrict__ Wimg,
    const float* __restrict__ bias,
    float* __restrict__ out) {

  __shared__ __align__(16) u16 Al[3][BM * BK];     // 3 x 4 KB bf16
  __shared__ __align__(16) u16 Bl[3][N_DIM * BK];  // 3 x 8 KB bf16

  const int tid  = threadIdx.x;
  const int lane = tid & 63;
  const int wid  = tid >> 6;
  const int wm   = wid >> 1;   // 0..1 : 32-row half
  const int wn   = wid & 1;    // 0..1 : 64-col half
  const int m0   = blockIdx.x * BM;
  const int l15  = lane & 15;
  const int lg   = lane >> 4;  // 0..3 : k-group (k = lg*8 + j)

  // A staging assignment: thread -> (row, k-chunk); Al granule (akc*64+arow)
  // holds x[m0+arow][t*32 + akc*8 .. +8] as bf16.
  const int arow = tid >> 2;   // 0..63
  const int akc  = tid & 3;    // 0..3
  const float* asrc = x + (size_t)(m0 + arow) * K_DIM + akc * 8;
  const int aoff = (akc * 64 + arow) * 8;   // halves offset within a slot

  f32x4 areg[2][2];            // 2-slot reg ring for A tiles in flight

#define LOADA(RS, T)                                        \
  do {                                                      \
    areg[RS][0] = *(const f32x4*)(asrc + (T) * 32);         \
    areg[RS][1] = *(const f32x4*)(asrc + (T) * 32 + 4);     \
  } while (0)

#define ISSUEB(T)                                                            \
  do {                                                                       \
    _Pragma("unroll")                                                        \
    for (int i = 0; i < 2; ++i) {                                            \
      int cd = i * 256 + tid;                                                \
      const u16* srcB = Wimg + (size_t)(T) * (N_DIM * BK) + cd * 8;          \
      __builtin_amdgcn_global_load_lds(                                      \
          (const __attribute__((address_space(1))) void*)srcB,               \
          (__attribute__((address_space(3))) void*)(&Bl[(T) % 3][cd * 8]),   \
          16, 0, 0);                                                         \
    }                                                                        \
  } while (0)

#define WRITEA(RS, T)                                                        \
  do {                                                                       \
    union { bf16x8 v; __hip_bfloat162 p[4]; } pa;                            \
    f32x4 r0 = areg[RS][0];                                                  \
    f32x4 r1 = areg[RS][1];                                                  \
    pa.p[0] = __float22bfloat162_rn(make_float2(r0[0], r0[1]));              \
    pa.p[1] = __float22bfloat162_rn(make_float2(r0[2], r0[3]));              \
    pa.p[2] = __float22bfloat162_rn(make_float2(r1[0], r1[1]));              \
    pa.p[3] = __float22bfloat162_rn(make_float2(r1[2], r1[3]));              \
    *(bf16x8*)(&Al[(T) % 3][aoff]) = pa.v;                                   \
  } while (0)

  f32x4 acc[2][4] = {};

  // Prologue. Queue (oldest->newest): A0,B0,A1,B1 = 8. vmcnt(6) retires A0.
  LOADA(0, 0);
  ISSUEB(0);
  LOADA(1, 1);
  ISSUEB(1);
  asm volatile("s_waitcnt vmcnt(6)" ::: "memory");
  WRITEA(0, 0);

#pragma unroll
  for (int t = 0; t < NT; ++t) {
    // Entering queue: B(t), A(t+1), B(t+1) = 6 (modulo benign reorder).
    // vmcnt(2) retires the 4 oldest -> B(t) LDS valid, A(t+1) regs valid.
    if (t + 1 < NT) asm volatile("s_waitcnt vmcnt(2)" ::: "memory");
    else            asm volatile("s_waitcnt vmcnt(0)" ::: "memory");

    // Commit A(t+1) to its ring slot; drain ds_write before the barrier.
    if (t + 1 < NT) {
      WRITEA((t + 1) & 1, t + 1);
      asm volatile("s_waitcnt lgkmcnt(0)" ::: "memory");
    }
    __builtin_amdgcn_sched_barrier(0);   // pin compute(t-1) reads/MFMAs above
    asm volatile("s_barrier" ::: "memory");

    // Issue tile t+2 AFTER the barrier: its B target buf (t+2)%3 == (t-1)%3,
    // which every wave has finished reading (compute(t-1) ended at barrier).
    if (t + 2 < NT) {
      LOADA(t & 1, t + 2);
      ISSUEB(t + 2);
    }

    // Compute tile t.
    const u16* Ab = &Al[t % 3][0];
    const u16* Bb = &Bl[t % 3][0];
    bf16x8 a[2];
#pragma unroll
    for (int q = 0; q < 2; ++q) {
      int row = wm * 32 + q * 16 + l15;
      a[q] = *(const bf16x8*)(Ab + (lg * 64 + row) * 8);
    }
#pragma unroll
    for (int f = 0; f < 4; ++f) {
      int col = wn * 64 + f * 16 + l15;
      bf16x8 bfr = *(const bf16x8*)(Bb + col * 32 + lg * 8);
#pragma unroll
      for (int q = 0; q < 2; ++q)
        acc[q][f] = __builtin_amdgcn_mfma_f32_16x16x32_bf16(a[q], bfr, acc[q][f], 0, 0, 0);
    }
  }
#undef LOADA
#undef ISSUEB
#undef WRITEA

  // epilogue: C/D layout col=lane&15, row=(lane>>4)*4+j
#pragma unroll
  for (int f = 0; f < 4; ++f) {
    const int gc = wn * 64 + f * 16 + l15;
    const float bq = pwbq(bias[gc]);
#pragma unroll
    for (int q = 0; q < 2; ++q) {
      const int gr0 = m0 + wm * 32 + q * 16 + lg * 4;
#pragma unroll
      for (int j = 0; j < 4; ++j)
        out[(size_t)(gr0 + j) * N_DIM + gc] = acc[q][f][j] + bq;
    }
  }
}

extern "C" void kernel_launch(void* const* d_in, const int* in_sizes, int n_in,
                              void* d_out, int out_size, void* d_ws, size_t ws_size,
                              hipStream_t stream) {
  const float* x = (const float*)d_in[0];
  const float* W = (const float*)d_in[1];
  const float* b = (const float*)d_in[2];
  float* out = (float*)d_out;

  const int M = in_sizes[0] / K_DIM;   // 32768
  const int grid = M / BM;             // 512

  const size_t need = (size_t)K_DIM * N_DIM * sizeof(u16);  // 256 KiB
  if (d_ws != nullptr && ws_size >= need) {
    u16* Wimg = (u16*)d_ws;
    quantW_kernel<<<(K_DIM * N_DIM) / 256, 256, 0, stream>>>(W, Wimg);
    pwb_gemm<<<grid, 256, 0, stream>>>(x, Wimg, b, out);
  } else {
    int total = M * N_DIM;
    naive_kernel<<<(total + 255) / 256, 256, 0, stream>>>(x, W, b, out, total);
  }
}